// Round 12
// baseline (325.096 us; speedup 1.0000x reference)
//
#include <hip/hip_runtime.h>
#include <hip/hip_bf16.h>

// MACE layer forward, MI355X (gfx950). f32 I/O, bf16 internals.
// Round 23: launch balancing. k_prep_spec was 47 blocks (~97% of CUs idle
// during that launch) while k_fill_pre carried 1890. The 1250 csr-fill
// blocks depend on NOTHING prep produces (only recv/cnt/csr) -> moved into
// k_prep_spec (now 1297 blocks: transposes || csr scatter overlap);
// k_fill_pre = 640 tile blocks only. Ordering preserved: csr done after
// prep; edge after fill. k_edge/k_post untouched (R22 equilibrium:
// fixed-stride CSR, EGRID 1024, 128 VGPR, ~135us).

#define NN 10000
#define EE 320000
#define CAP 128
#define FEPS 0.17677669529663687f

typedef __attribute__((ext_vector_type(4))) float f32x4;
typedef __attribute__((ext_vector_type(8))) short s16x8;

__device__ __forceinline__ float bflo(unsigned u) { return __uint_as_float(u << 16); }
__device__ __forceinline__ float bfhi(unsigned u) { return __uint_as_float(u & 0xffff0000u); }
__device__ __forceinline__ unsigned short f2bu(float f) {
    unsigned u = __float_as_uint(f);
    return (unsigned short)((u + 0x7FFFu + ((u >> 16) & 1u)) >> 16);
}
__device__ __forceinline__ unsigned pack2(float a, float b) {
    return (unsigned)f2bu(a) | ((unsigned)f2bu(b) << 16);
}
__device__ __forceinline__ s16x8 pack8(float4 a, float4 b) {
    union { s16x8 v; unsigned short u[8]; } r;
    r.u[0] = f2bu(a.x); r.u[1] = f2bu(a.y); r.u[2] = f2bu(a.z); r.u[3] = f2bu(a.w);
    r.u[4] = f2bu(b.x); r.u[5] = f2bu(b.y); r.u[6] = f2bu(b.z); r.u[7] = f2bu(b.w);
    return r.v;
}

// ---- prep: weight transposes + w2t + species buckets + csr fill ----
#define TWN (26 * 16384)
#define W2N (640 * 64)
#define PREPX 20
#define HISTB 1250
__global__ __launch_bounds__(256) void k_prep_spec(
    const float* __restrict__ Wus, const float* __restrict__ Wuv,
    const float* __restrict__ Wds, const float* __restrict__ Wdv,
    const float* __restrict__ Wls, const float* __restrict__ Wlv,
    const float* __restrict__ Wss, const float* __restrict__ Wsv,
    const float* __restrict__ W_rad2,
    unsigned short* __restrict__ T,
    unsigned short* __restrict__ w2t,
    const int* __restrict__ specie, int* __restrict__ perm,
    int2* __restrict__ tiles, int* __restrict__ ntiles,
    const int* __restrict__ recv, int* __restrict__ cnt,
    int* __restrict__ csr) {
    const int b = blockIdx.x, tid = threadIdx.x;
    if (b < 26) {
        __shared__ unsigned short tr[128][130];  // pad 130: 2-way free
        const int m = b;
        const float* src;
        if (m == 0) src = Wus; else if (m == 1) src = Wuv;
        else if (m == 2) src = Wds; else if (m == 3) src = Wdv;
        else if (m == 4) src = Wls; else if (m == 5) src = Wlv;
        else if (m < 16) src = Wss + (size_t)(m - 6) * 16384;
        else src = Wsv + (size_t)(m - 16) * 16384;
        for (int i = tid; i < 16384; i += 256) {
            const int c = i >> 7, d = i & 127;   // coalesced read of src[c][d]
            tr[d][c] = f2bu(src[i]);
        }
        __syncthreads();
        unsigned* o32 = (unsigned*)(T + (size_t)m * 16384);
        for (int i = tid; i < 8192; i += 256) {  // coalesced u32 write
            const int d = i >> 6, c2 = (i & 63) * 2;
            o32[i] = (unsigned)tr[d][c2] | ((unsigned)tr[d][c2 + 1] << 16);
        }
    } else if (b < 26 + PREPX) {
        for (int i = (b - 26) * 256 + tid; i < W2N; i += PREPX * 256) {
            const int n = i >> 6, k = i & 63;
            w2t[i] = f2bu(W_rad2[k * 640 + n]);
        }
    } else if (b == 26 + PREPX) {
        // species buckets: hist + tiles + perm (one block, LDS atomics)
        __shared__ int hcnt[10], hbase[10], hcur[10], tbase[11];
        if (tid < 10) hcnt[tid] = 0;
        __syncthreads();
        for (int n = tid; n < NN; n += 256) {
            int s = specie[n];
            s = ((unsigned)s < 10) ? s : 0;
            atomicAdd(&hcnt[s], 1);
        }
        __syncthreads();
        if (tid == 0) {
            int run = 0, tc = 0;
            for (int sp = 0; sp < 10; sp++) {
                hbase[sp] = run; hcur[sp] = run; run += hcnt[sp];
                tbase[sp] = tc;  tc += (hcnt[sp] + 15) >> 4;
            }
            tbase[10] = tc;
            *ntiles = tc;
        }
        __syncthreads();
        const int tc = tbase[10];
        for (int ti = tid; ti < tc; ti += 256) {
            int sp = 0;
            while (sp < 9 && ti >= tbase[sp + 1]) sp++;
            const int bb = (ti - tbase[sp]) * 16;
            tiles[ti] = make_int2(hbase[sp] + bb, (sp << 8) | min(16, hcnt[sp] - bb));
        }
        for (int n = tid; n < NN; n += 256) {
            int s = specie[n];
            s = ((unsigned)s < 10) ? s : 0;
            int slot = atomicAdd(&hcur[s], 1);
            if ((unsigned)slot < NN) perm[slot] = n;
        }
    } else {  // direct csr fill (independent of everything above)
        const int e = (b - (26 + PREPX + 1)) * 256 + tid;
        if (e < EE) {
            int r = recv[e];
            r = ((unsigned)r < NN) ? r : 0;
            int slot = atomicAdd(&cnt[r], 1);
            if (slot < CAP) csr[(r << 7) + slot] = e;
        }
    }
}

// ---- pre: perm-tiles, h4q (W_up) + scb (W_skip[sp]) ----
// h4q: uint4[NN][64]; pair P=16*(d>>5)+(d&15) holds channels c=32wv+row
// (half 0) and c+16 (half 1), each as uint2{pack2(s,v0),pack2(v1,v2)}.
// scb: uint2[NN][128] = {pack2(sc_s,sc_v0), pack2(sc_v1,sc_v2)}.
__global__ __launch_bounds__(256) void k_fill_pre(
    const float* __restrict__ nf,
    const unsigned short* __restrict__ Tw,
    uint2* __restrict__ h4o,
    const int* __restrict__ perm, const int2* __restrict__ tiles,
    const int* __restrict__ ntiles,
    uint2* __restrict__ scb) {
    const int tile = blockIdx.x;
    if (tile >= *ntiles) return;
    const int2 td = tiles[tile];
    const int base = td.x, sp = td.y >> 8, cnt16 = td.y & 255;
    __shared__ int nodesl[16];
    __shared__ float nfl[16][516];  // pad 516: 2-way banks (was 16-way)
    const int tid = threadIdx.x;
    if (tid < 16) nodesl[tid] = perm[base + ((tid < cnt16) ? tid : 0)];
    __syncthreads();
    {
        for (int i = tid; i < 2048; i += 256) {
            const int r = i >> 7, off4 = (i & 127) * 4;
            *(float4*)&nfl[r][off4] =
                ((const float4*)(nf + (size_t)nodesl[r] * 512))[i & 127];
        }
    }
    __syncthreads();
    const int lane = tid & 63, wv = tid >> 6;
    const int col = lane & 15, quad = lane >> 4;
    const float* rp = nfl[col];
    s16x8 Af[4][4];
#pragma unroll
    for (int kt = 0; kt < 4; kt++) {
        const int ko = kt * 32 + quad * 8;
        const float4 fa = *(const float4*)(rp + ko);
        const float4 fb = *(const float4*)(rp + ko + 4);
        Af[0][kt] = pack8(fa, fb);
#pragma unroll
        for (int i = 0; i < 3; i++) {
            union { s16x8 v; unsigned short u[8]; } A;
#pragma unroll
            for (int j = 0; j < 8; j++) A.u[j] = f2bu(rp[128 + 3 * (ko + j) + i]);
            Af[1 + i][kt] = A.v;
        }
    }
    const unsigned short* Ts = Tw;
    const unsigned short* Tv = Tw + 16384;
    const unsigned short* Tss = Tw + (size_t)(6 + sp) * 16384;
    const unsigned short* Tsv = Tw + (size_t)(16 + sp) * 16384;
#pragma unroll
    for (int nt = 0; nt < 2; nt++) {
        const int d = 32 * wv + 16 * nt + col;
        // ---- up GEMM -> h4q ----
        f32x4 C[4];
#pragma unroll
        for (int m = 0; m < 4; m++) C[m] = (f32x4){0.f, 0.f, 0.f, 0.f};
#pragma unroll
        for (int kt = 0; kt < 4; kt++) {
            const int ko = kt * 32 + quad * 8;
            const s16x8 Bs = *(const s16x8*)&Ts[(size_t)d * 128 + ko];
            const s16x8 Bv = *(const s16x8*)&Tv[(size_t)d * 128 + ko];
            C[0] = __builtin_amdgcn_mfma_f32_16x16x32_bf16(Af[0][kt], Bs, C[0], 0, 0, 0);
#pragma unroll
            for (int i = 0; i < 3; i++)
                C[1 + i] = __builtin_amdgcn_mfma_f32_16x16x32_bf16(Af[1 + i][kt], Bv, C[1 + i], 0, 0, 0);
        }
        const int P = ((d >> 5) << 4) + (d & 15);
        const int half = (d >> 4) & 1;
#pragma unroll
        for (int reg = 0; reg < 4; reg++) {
            const int node = nodesl[quad * 4 + reg];
            h4o[((size_t)node * 64 + P) * 2 + half] =
                make_uint2(pack2(C[0][reg], C[1][reg]), pack2(C[2][reg], C[3][reg]));
        }
        // ---- skip GEMM -> scb ----
        f32x4 CS[4];
#pragma unroll
        for (int m = 0; m < 4; m++) CS[m] = (f32x4){0.f, 0.f, 0.f, 0.f};
#pragma unroll
        for (int kt = 0; kt < 4; kt++) {
            const int ko = kt * 32 + quad * 8;
            const s16x8 Bss = *(const s16x8*)&Tss[(size_t)d * 128 + ko];
            const s16x8 Bsv = *(const s16x8*)&Tsv[(size_t)d * 128 + ko];
            CS[0] = __builtin_amdgcn_mfma_f32_16x16x32_bf16(Af[0][kt], Bss, CS[0], 0, 0, 0);
#pragma unroll
            for (int i = 0; i < 3; i++)
                CS[1 + i] = __builtin_amdgcn_mfma_f32_16x16x32_bf16(Af[1 + i][kt], Bsv, CS[1 + i], 0, 0, 0);
        }
#pragma unroll
        for (int reg = 0; reg < 4; reg++) {
            const int node = nodesl[quad * 4 + reg];
            scb[(size_t)node * 128 + d] =
                make_uint2(pack2(CS[0][reg], CS[1][reg]), pack2(CS[2][reg], CS[3][reg]));
        }
    }
}

// ------- MFMA edge kernel: 1-barrier/chunk pipeline + gather lookahead ------
#define EGRID 1024
__global__ __launch_bounds__(256, 2) void k_edge_mfma(
    const float* __restrict__ vectors,
    const float* __restrict__ radial,
    const int* __restrict__ senders,
    const float* __restrict__ W_rad1,
    const unsigned short* __restrict__ w2t,   // [640][64] bf16
    const uint4* __restrict__ h4q,            // [N][64] channel pairs
    const int* __restrict__ cnt, const int* __restrict__ csr,
    unsigned short* __restrict__ aggb) {      // [N][4][128] bf16 planar
    __shared__ unsigned short w1s[512];
    __shared__ float4 em[3][64];              // 3-slot rotation
    __shared__ float radl[3][64][8];
    __shared__ unsigned short hidb[2 * 64 * 72];  // double buffer
    const int tid = threadIdx.x;
    const int lane = tid & 63, wv = tid >> 6;
    const int row = lane & 15, quad = lane >> 4;
    const int sE = tid >> 2, st = tid & 3;    // stager/hid mapping
    for (int i = tid; i < 512; i += 256) w1s[i] = f2bu(W_rad1[i]);

    s16x8 Bf[2][5][2];
#pragma unroll
    for (int ti = 0; ti < 2; ti++) {
        const int t = 2 * wv + ti;
#pragma unroll
        for (int p = 0; p < 5; p++) {
            const unsigned short* bp =
                w2t + (size_t)(128 * p + 16 * t + row) * 64 + quad * 8;
            Bf[ti][p][0] = *(const s16x8*)(bp);
            Bf[ti][p][1] = *(const s16x8*)(bp + 32);
        }
    }

    // chunk iterator state: cur (computing), nxt (staging), nx2 (csr prefetch)
    // base = N<<7 (fixed-stride CSR), deg = min(cnt[N], CAP)
    int curN = blockIdx.x, curS = curN << 7, curD = min(cnt[curN], CAP), curC0 = 0;
    int nxtN = curN, nxtS = curS, nxtD = curD, nxtC0 = 0;
    {   // adv(nxt)
        nxtC0 += 64;
        if (nxtC0 >= nxtD) {
            nxtN += EGRID;
            if (nxtN < NN) { nxtS = nxtN << 7; nxtD = min(cnt[nxtN], CAP); }
            nxtC0 = 0;
        }
    }
    int nx2N = nxtN, nx2S = nxtS, nx2D = nxtD, nx2C0 = nxtC0;
    if (nx2N < NN) {  // adv(nx2)
        nx2C0 += 64;
        if (nx2C0 >= nx2D) {
            nx2N += EGRID;
            if (nx2N < NN) { nx2S = nx2N << 7; nx2D = min(cnt[nx2N], CAP); }
            nx2C0 = 0;
        }
    }

    // prologue: stage chunk 0 into slot 0 (direct)
    if (st < 2) {
        const int gi = curC0 + sE;
        if (gi < curD) {
            int e = csr[curS + gi];
            e = ((unsigned)e < EE) ? e : 0;
            if (st == 0) {
                int j = senders[e];
                j = ((unsigned)j < NN) ? j : 0;
                const float vx = vectors[e * 3 + 0];
                const float vy = vectors[e * 3 + 1];
                const float vz = vectors[e * 3 + 2];
                const float inr = 1.7320508075688772f /
                    (sqrtf(vx * vx + vy * vy + vz * vz) + 1e-9f);
                em[0][sE] = make_float4(__int_as_float(j), vx * inr, vy * inr, vz * inr);
            } else {
                *(float4*)&radl[0][sE][0] = *(const float4*)(radial + (size_t)e * 8);
                *(float4*)&radl[0][sE][4] = *(const float4*)(radial + (size_t)e * 8 + 4);
            }
        } else {
            if (st == 0) em[0][sE] = make_float4(0.f, 0.f, 0.f, 0.f);
            else {
                *(float4*)&radl[0][sE][0] = make_float4(0.f, 0.f, 0.f, 0.f);
                *(float4*)&radl[0][sE][4] = make_float4(0.f, 0.f, 0.f, 0.f);
            }
        }
    }
    // prologue csr lookahead for chunk 1 (nxt)
    int eReg = -1;
    if (nxtN < NN && st < 2) {
        const int gi = nxtC0 + sE;
        if (gi < nxtD) {
            int e = csr[nxtS + gi];
            eReg = ((unsigned)e < EE) ? e : 0;
        }
    }
    __syncthreads();

    float acc_s[2] = {0.f, 0.f}, av0[2] = {0.f, 0.f},
          av1[2] = {0.f, 0.f}, av2[2] = {0.f, 0.f};
    int cs = 0, hbI = 0;
    while (true) {
        const int ws = (cs == 2) ? 0 : cs + 1;
        const bool hasNxt = (nxtN < NN);
        const float4* emc = em[cs];
        const float* emf = (const float*)emc;
        // ---- A0: issue group-0 h4q gathers for CURRENT chunk (em[cs] is
        //      valid since the previous barrier) -> in flight across B/C ----
        uint4 hqA[4];
#pragma unroll
        for (int rg = 0; rg < 4; rg++) {
            const int j = __float_as_int(emf[(quad * 4 + rg) * 4]);
            hqA[rg] = h4q[(size_t)j * 64 + (wv << 4) + row];
        }
        // ---- A1: gathers for next chunk from eReg; csr prefetch for nx2 ----
        bool sv = false;
        float4 ra0 = make_float4(0.f, 0.f, 0.f, 0.f);
        float4 ra1 = make_float4(0.f, 0.f, 0.f, 0.f);
        if (hasNxt && st < 2 && eReg >= 0) {
            sv = true;
            const int e = eReg;
            if (st == 0) {
                int j = senders[e];
                j = ((unsigned)j < NN) ? j : 0;
                ra0 = make_float4(vectors[e * 3 + 0], vectors[e * 3 + 1],
                                  vectors[e * 3 + 2], __int_as_float(j));
            } else {
                ra0 = *(const float4*)(radial + (size_t)e * 8);
                ra1 = *(const float4*)(radial + (size_t)e * 8 + 4);
            }
        }
        int eRegN = -1;
        if (nx2N < NN && st < 2) {
            const int gi = nx2C0 + sE;
            if (gi < nx2D) {
                int e = csr[nx2S + gi];
                eRegN = ((unsigned)e < EE) ? e : 0;
            }
        }
        // ---- B: hid MLP for current chunk (skip empty slots) ----
        const int glimC = min(64, curD - curC0);
        {
            const int g16C = (glimC + 15) & ~15;
            unsigned short* hb = hidb + hbI * 4608;
            const int u0 = st * 16;
            if (sE < glimC) {
                float rr[8];
                *(float4*)&rr[0] = *(const float4*)&radl[cs][sE][0];
                *(float4*)&rr[4] = *(const float4*)&radl[cs][sE][4];
#pragma unroll
                for (int h = 0; h < 2; h++) {
                    float a[8];
#pragma unroll
                    for (int u = 0; u < 8; u++) a[u] = 0.f;
#pragma unroll
                    for (int r = 0; r < 8; r++) {
                        const uint4 wa = *(const uint4*)&w1s[r * 64 + u0 + h * 8];
                        const float f = rr[r];
                        a[0] += f * bflo(wa.x); a[1] += f * bfhi(wa.x);
                        a[2] += f * bflo(wa.y); a[3] += f * bfhi(wa.y);
                        a[4] += f * bflo(wa.z); a[5] += f * bfhi(wa.z);
                        a[6] += f * bflo(wa.w); a[7] += f * bfhi(wa.w);
                    }
                    unsigned o[4];
#pragma unroll
                    for (int k = 0; k < 4; k++) {
                        const float s0 = a[2 * k] / (1.f + __expf(-a[2 * k]));
                        const float s1 = a[2 * k + 1] / (1.f + __expf(-a[2 * k + 1]));
                        o[k] = pack2(s0, s1);
                    }
                    *(uint4*)&hb[sE * 72 + u0 + h * 8] = make_uint4(o[0], o[1], o[2], o[3]);
                }
            } else if (sE < g16C) {
                *(uint4*)&hb[sE * 72 + u0] = make_uint4(0, 0, 0, 0);
                *(uint4*)&hb[sE * 72 + u0 + 8] = make_uint4(0, 0, 0, 0);
            }
        }
        // ---- C: store staged data for next chunk ----
        if (hasNxt && st < 2) {
            if (st == 0) {
                if (sv) {
                    const float vx = ra0.x, vy = ra0.y, vz = ra0.z;
                    const float inr = 1.7320508075688772f /
                        (sqrtf(vx * vx + vy * vy + vz * vz) + 1e-9f);
                    em[ws][sE] = make_float4(ra0.w, vx * inr, vy * inr, vz * inr);
                } else {
                    em[ws][sE] = make_float4(0.f, 0.f, 0.f, 0.f);
                }
            } else {
                *(float4*)&radl[ws][sE][0] = ra0;
                *(float4*)&radl[ws][sE][4] = ra1;
            }
        }
        __syncthreads();
        // ---- E: MFMA + combine for current chunk (boosted priority) ----
        {
            __builtin_amdgcn_s_setprio(1);
            const unsigned short* hb = hidb + hbI * 4608;
            for (int g0 = 0; g0 < glimC; g0 += 16) {
                const s16x8 A0 = *(const s16x8*)&hb[(g0 + row) * 72 + quad * 8];
                const s16x8 A1 = *(const s16x8*)&hb[(g0 + row) * 72 + 32 + quad * 8];
                float4 mm[4];
#pragma unroll
                for (int rg = 0; rg < 4; rg++) mm[rg] = emc[g0 + quad * 4 + rg];
                // prefetch next group's h4q rows
                const bool more = (g0 + 16) < glimC;
                uint4 hqB[4];
                if (more) {
#pragma unroll
                    for (int rg = 0; rg < 4; rg++) {
                        const int j = __float_as_int(emf[(g0 + 16 + quad * 4 + rg) * 4]);
                        hqB[rg] = h4q[(size_t)j * 64 + (wv << 4) + row];
                    }
                }
#pragma unroll
                for (int ti = 0; ti < 2; ti++) {
                    float sj[4], a0r[4], a1r[4], a2r[4];
#pragma unroll
                    for (int rg = 0; rg < 4; rg++) {
                        const unsigned wx = ti ? hqA[rg].z : hqA[rg].x;
                        const unsigned wy = ti ? hqA[rg].w : hqA[rg].y;
                        sj[rg] = bflo(wx); a0r[rg] = bfhi(wx);
                        a1r[rg] = bflo(wy); a2r[rg] = bfhi(wy);
                    }
#pragma unroll
                    for (int p = 0; p < 5; p++) {
                        f32x4 z = {0.f, 0.f, 0.f, 0.f};
                        z = __builtin_amdgcn_mfma_f32_16x16x32_bf16(A0, Bf[ti][p][0], z, 0, 0, 0);
                        z = __builtin_amdgcn_mfma_f32_16x16x32_bf16(A1, Bf[ti][p][1], z, 0, 0, 0);
#pragma unroll
                        for (int rg = 0; rg < 4; rg++) {
                            const float w = z[rg];
                            const float y0 = mm[rg].y, y1 = mm[rg].z, y2 = mm[rg].w;
                            if (p == 0) {
                                acc_s[ti] += w * sj[rg];
                            } else if (p == 1) {
                                const float wsj = w * sj[rg];
                                av0[ti] += wsj * y0;
                                av1[ti] += wsj * y1;
                                av2[ti] += wsj * y2;
                            } else if (p == 2) {
                                av0[ti] += w * a0r[rg];
                                av1[ti] += w * a1r[rg];
                                av2[ti] += w * a2r[rg];
                            } else if (p == 3) {
                                acc_s[ti] += w * (a0r[rg] * y0 + a1r[rg] * y1 +
                                                  a2r[rg] * y2);
                            } else {
                                av0[ti] += w * (a1r[rg] * y2 - a2r[rg] * y1);
                                av1[ti] += w * (a2r[rg] * y0 - a0r[rg] * y2);
                                av2[ti] += w * (a0r[rg] * y1 - a1r[rg] * y0);
                            }
                        }
                    }
                }
                if (more) {
#pragma unroll
                    for (int rg = 0; rg < 4; rg++) hqA[rg] = hqB[rg];
                }
            }
            __builtin_amdgcn_s_setprio(0);
            // finalize node on its last chunk
            if (curC0 + 64 >= curD) {
#pragma unroll
                for (int ti = 0; ti < 2; ti++) {
                    acc_s[ti] += __shfl_xor(acc_s[ti], 16); acc_s[ti] += __shfl_xor(acc_s[ti], 32);
                    av0[ti] += __shfl_xor(av0[ti], 16);     av0[ti] += __shfl_xor(av0[ti], 32);
                    av1[ti] += __shfl_xor(av1[ti], 16);     av1[ti] += __shfl_xor(av1[ti], 32);
                    av2[ti] += __shfl_xor(av2[ti], 16);     av2[ti] += __shfl_xor(av2[ti], 32);
                }
                if (lane < 16) {
                    unsigned short* og = aggb + (size_t)curN * 512;
#pragma unroll
                    for (int ti = 0; ti < 2; ti++) {
                        const int cc = 16 * (2 * wv + ti) + lane;
                        og[cc] = f2bu(acc_s[ti]);
                        og[128 + cc] = f2bu(av0[ti]);
                        og[256 + cc] = f2bu(av1[ti]);
                        og[384 + cc] = f2bu(av2[ti]);
                    }
                }
                acc_s[0] = acc_s[1] = 0.f; av0[0] = av0[1] = 0.f;
                av1[0] = av1[1] = 0.f;     av2[0] = av2[1] = 0.f;
            }
        }
        if (!hasNxt) break;
        // advance: cur <- nxt, nxt <- nx2, adv(nx2), eReg <- eRegN
        curN = nxtN; curS = nxtS; curD = nxtD; curC0 = nxtC0;
        nxtN = nx2N; nxtS = nx2S; nxtD = nx2D; nxtC0 = nx2C0;
        if (nx2N < NN) {
            nx2C0 += 64;
            if (nx2C0 >= nx2D) {
                nx2N += EGRID;
                if (nx2N < NN) { nx2S = nx2N << 7; nx2D = min(cnt[nx2N], CAP); }
                nx2C0 = 0;
            }
        }
        eReg = eRegN;
        cs = ws; hbI ^= 1;
    }
}

// -------- post: down GEMM -> prod -> P via LDS -> lin GEMM + scb + out -----
__global__ __launch_bounds__(256) void k_post_mfma(
    const unsigned short* __restrict__ aggb,
    const int* __restrict__ perm,
    const int2* __restrict__ tiles,
    const int* __restrict__ ntiles,
    const unsigned short* __restrict__ Tw,
    const float* __restrict__ Wps,
    const float* __restrict__ Wpv,
    const float* __restrict__ Wro,
    const uint2* __restrict__ scb,
    float* __restrict__ dout) {
    const int tile = blockIdx.x;
    if (tile >= *ntiles) return;
    const int2 td = tiles[tile];
    const int base = td.x, sp = td.y >> 8, cnt = td.y & 255;
    __shared__ int nodesl[16];
    __shared__ float rol[16];
    __shared__ unsigned short Pl[4][16][136];  // pad 136: 16B-aligned, 2-way
    const int tid = threadIdx.x;
    if (tid < 16) {
        nodesl[tid] = perm[base + ((tid < cnt) ? tid : 0)];
        rol[tid] = 0.f;
    }
    __syncthreads();
    const int lane = tid & 63, wv = tid >> 6;
    const int col = lane & 15, quad = lane >> 4;
    const int aN = nodesl[col];
    const unsigned short* Tds = Tw + (size_t)2 * 16384;
    const unsigned short* Tdv = Tw + (size_t)3 * 16384;
    const unsigned short* Tls = Tw + (size_t)4 * 16384;
    const unsigned short* Tlv = Tw + (size_t)5 * 16384;
#pragma unroll
    for (int nt = 0; nt < 2; nt++) {
        const int d = 32 * wv + 16 * nt + col;
        f32x4 CF[4];
#pragma unroll
        for (int m = 0; m < 4; m++) CF[m] = (f32x4){0.f, 0.f, 0.f, 0.f};
#pragma unroll
        for (int kt = 0; kt < 4; kt++) {
            const int ko = kt * 32 + quad * 8;
            const s16x8 Bs = *(const s16x8*)&Tds[(size_t)d * 128 + ko];
            const s16x8 Bv = *(const s16x8*)&Tdv[(size_t)d * 128 + ko];
#pragma unroll
            for (int m = 0; m < 4; m++) {
                const s16x8 A = *(const s16x8*)&aggb[(size_t)aN * 512 + m * 128 + ko];
                CF[m] = __builtin_amdgcn_mfma_f32_16x16x32_bf16(A, m ? Bv : Bs, CF[m], 0, 0, 0);
            }
        }
        const float wps0 = Wps[sp * 384 + d];
        const float wps1 = Wps[sp * 384 + 128 + d];
        const float wps2 = Wps[sp * 384 + 256 + d];
        const float wpv0 = Wpv[sp * 256 + d];
        const float wpv1 = Wpv[sp * 256 + 128 + d];
#pragma unroll
        for (int reg = 0; reg < 4; reg++) {
            const float fs = CF[0][reg] * FEPS;
            const float f0 = CF[1][reg] * FEPS;
            const float f1 = CF[2][reg] * FEPS;
            const float f2 = CF[3][reg] * FEPS;
            const float ps = fs * wps0 + fs * fs * wps1 + (f0 * f0 + f1 * f1 + f2 * f2) * wps2;
            const float pb = wpv0 + fs * wpv1;
            const int r = quad * 4 + reg;
            Pl[0][r][d] = f2bu(ps);
            Pl[1][r][d] = f2bu(f0 * pb);
            Pl[2][r][d] = f2bu(f1 * pb);
            Pl[3][r][d] = f2bu(f2 * pb);
        }
    }
    __syncthreads();
#pragma unroll
    for (int nt = 0; nt < 2; nt++) {
        const int d = 32 * wv + 16 * nt + col;
        f32x4 CL[4];
#pragma unroll
        for (int m = 0; m < 4; m++) CL[m] = (f32x4){0.f, 0.f, 0.f, 0.f};
#pragma unroll
        for (int kt = 0; kt < 4; kt++) {
            const int ko = kt * 32 + quad * 8;
            const s16x8 Bls = *(const s16x8*)&Tls[(size_t)d * 128 + ko];
            const s16x8 Blv = *(const s16x8*)&Tlv[(size_t)d * 128 + ko];
#pragma unroll
            for (int m = 0; m < 4; m++) {
                const s16x8 A = *(const s16x8*)&Pl[m][col][ko];
                CL[m] = __builtin_amdgcn_mfma_f32_16x16x32_bf16(A, m ? Blv : Bls, CL[m], 0, 0, 0);
            }
        }
        const float wro = Wro[d];
#pragma unroll
        for (int reg = 0; reg < 4; reg++) {
            const int r = quad * 4 + reg;
            if (r < cnt) {
                const int node = nodesl[r];
                const uint2 sv = scb[(size_t)node * 128 + d];
                const float outs = CL[0][reg] + bflo(sv.x);
                const float o0 = CL[1][reg] + bfhi(sv.x);
                const float o1 = CL[2][reg] + bflo(sv.y);
                const float o2 = CL[3][reg] + bfhi(sv.y);
                float* o = dout + NN + (size_t)node * 512;
                o[d] = outs;
                o[128 + 3 * d + 0] = o0;
                o[128 + 3 * d + 1] = o1;
                o[128 + 3 * d + 2] = o2;
                atomicAdd(&rol[r], outs * wro);
            }
        }
    }
    __syncthreads();
    if (tid < 16 && tid < cnt) dout[nodesl[tid]] = rol[tid];
}

extern "C" void kernel_launch(void* const* d_in, const int* in_sizes, int n_in,
                              void* d_out, int out_size, void* d_ws, size_t ws_size,
                              hipStream_t stream) {
    const float* vectors    = (const float*)d_in[0];
    const float* node_feats = (const float*)d_in[1];
    const int*   specie     = (const int*)d_in[2];
    const float* radial     = (const float*)d_in[3];
    const int*   senders    = (const int*)d_in[4];
    const int*   receivers  = (const int*)d_in[5];
    const float* W_up_s     = (const float*)d_in[6];
    const float* W_up_v     = (const float*)d_in[7];
    const float* W_rad1     = (const float*)d_in[8];
    const float* W_rad2     = (const float*)d_in[9];
    const float* W_down_s   = (const float*)d_in[10];
    const float* W_down_v   = (const float*)d_in[11];
    const float* W_skip_s   = (const float*)d_in[12];
    const float* W_skip_v   = (const float*)d_in[13];
    const float* W_prod_s   = (const float*)d_in[14];
    const float* W_prod_v   = (const float*)d_in[15];
    const float* W_lin_s    = (const float*)d_in[16];
    const float* W_lin_v    = (const float*)d_in[17];
    const float* W_ro       = (const float*)d_in[18];
    float* out = (float*)d_out;

    // workspace carve (~37 MB)
    char* w = (char*)d_ws;
    auto align256 = [](size_t x) { return (x + 255) & ~(size_t)255; };
    int* cnt  = (int*)w;              w += align256((size_t)NN * 4);
    int* csr  = (int*)w;              w += align256((size_t)NN * CAP * 4);
    uint4* h4q = (uint4*)w;           w += align256((size_t)NN * 64 * 16);
    unsigned short* aggb = (unsigned short*)w;  w += align256((size_t)NN * 512 * 2);
    unsigned short* w2t  = (unsigned short*)w;  w += align256((size_t)W2N * 2);
    unsigned short* Tw   = (unsigned short*)w;  w += align256((size_t)TWN * 2);
    int* perm   = (int*)w;            w += align256((size_t)NN * 4);
    int2* tiles = (int2*)w;           w += align256((size_t)640 * 8);
    int* ntiles = (int*)w;            w += align256(4);
    uint2* scb  = (uint2*)w;          w += align256((size_t)NN * 128 * 8);

    hipMemsetAsync(cnt, 0, (size_t)NN * 4, stream);
    k_prep_spec<<<26 + PREPX + 1 + HISTB, 256, 0, stream>>>(
        W_up_s, W_up_v, W_down_s, W_down_v, W_lin_s, W_lin_v,
        W_skip_s, W_skip_v, W_rad2, Tw, w2t, specie, perm, tiles, ntiles,
        receivers, cnt, csr);
    k_fill_pre<<<640, 256, 0, stream>>>(
        node_feats, Tw, (uint2*)h4q, perm, tiles, ntiles, scb);
    k_edge_mfma<<<EGRID, 256, 0, stream>>>(vectors, radial, senders, W_rad1,
                                           w2t, h4q, cnt, csr, aggb);
    k_post_mfma<<<640, 256, 0, stream>>>(aggb, perm, tiles, ntiles,
                                         Tw, W_prod_s, W_prod_v, W_ro, scb, out);
}

// Round 13
// 318.347 us; speedup vs baseline: 1.0212x; 1.0212x over previous
//
#include <hip/hip_runtime.h>
#include <hip/hip_bf16.h>

// MACE layer forward, MI355X (gfx950). f32 I/O, bf16 internals.
// Round 24: consolidation on R22 (best measured 323.9; R23's prep||csr
// rebalance was neutral-to-worse within the +-6us noise band -> reverted).
// One zero-risk micro added: k_post prefetches all 16 scb gathers before
// the lin-GEMM phase (latency hidden under 32 MFMAs; nodesl clamped so
// unguarded addressing is safe). Structure: memset -> prep(47) ->
// fill(640 tiles + 1250 csr) -> edge(1024, fixed-stride CSR) -> post(640).
// k_edge at its structural optimum: 128-VGPR cross-barrier envelope full
// (R12/R16 spills), gather chains at max cover (A0/hqB/eReg lookahead).

#define NN 10000
#define EE 320000
#define CAP 128
#define FEPS 0.17677669529663687f

typedef __attribute__((ext_vector_type(4))) float f32x4;
typedef __attribute__((ext_vector_type(8))) short s16x8;

__device__ __forceinline__ float bflo(unsigned u) { return __uint_as_float(u << 16); }
__device__ __forceinline__ float bfhi(unsigned u) { return __uint_as_float(u & 0xffff0000u); }
__device__ __forceinline__ unsigned short f2bu(float f) {
    unsigned u = __float_as_uint(f);
    return (unsigned short)((u + 0x7FFFu + ((u >> 16) & 1u)) >> 16);
}
__device__ __forceinline__ unsigned pack2(float a, float b) {
    return (unsigned)f2bu(a) | ((unsigned)f2bu(b) << 16);
}
__device__ __forceinline__ s16x8 pack8(float4 a, float4 b) {
    union { s16x8 v; unsigned short u[8]; } r;
    r.u[0] = f2bu(a.x); r.u[1] = f2bu(a.y); r.u[2] = f2bu(a.z); r.u[3] = f2bu(a.w);
    r.u[4] = f2bu(b.x); r.u[5] = f2bu(b.y); r.u[6] = f2bu(b.z); r.u[7] = f2bu(b.w);
    return r.v;
}

// ---- prep: weight transposes + w2t + species buckets ----
#define TWN (26 * 16384)
#define W2N (640 * 64)
#define PREPX 20
#define HISTB 1250
__global__ __launch_bounds__(256) void k_prep_spec(
    const float* __restrict__ Wus, const float* __restrict__ Wuv,
    const float* __restrict__ Wds, const float* __restrict__ Wdv,
    const float* __restrict__ Wls, const float* __restrict__ Wlv,
    const float* __restrict__ Wss, const float* __restrict__ Wsv,
    const float* __restrict__ W_rad2,
    unsigned short* __restrict__ T,
    unsigned short* __restrict__ w2t,
    const int* __restrict__ specie, int* __restrict__ perm,
    int2* __restrict__ tiles, int* __restrict__ ntiles) {
    const int b = blockIdx.x, tid = threadIdx.x;
    if (b < 26) {
        __shared__ unsigned short tr[128][130];  // pad 130: 2-way free
        const int m = b;
        const float* src;
        if (m == 0) src = Wus; else if (m == 1) src = Wuv;
        else if (m == 2) src = Wds; else if (m == 3) src = Wdv;
        else if (m == 4) src = Wls; else if (m == 5) src = Wlv;
        else if (m < 16) src = Wss + (size_t)(m - 6) * 16384;
        else src = Wsv + (size_t)(m - 16) * 16384;
        for (int i = tid; i < 16384; i += 256) {
            const int c = i >> 7, d = i & 127;   // coalesced read of src[c][d]
            tr[d][c] = f2bu(src[i]);
        }
        __syncthreads();
        unsigned* o32 = (unsigned*)(T + (size_t)m * 16384);
        for (int i = tid; i < 8192; i += 256) {  // coalesced u32 write
            const int d = i >> 6, c2 = (i & 63) * 2;
            o32[i] = (unsigned)tr[d][c2] | ((unsigned)tr[d][c2 + 1] << 16);
        }
    } else if (b < 26 + PREPX) {
        for (int i = (b - 26) * 256 + tid; i < W2N; i += PREPX * 256) {
            const int n = i >> 6, k = i & 63;
            w2t[i] = f2bu(W_rad2[k * 640 + n]);
        }
    } else {  // species buckets: hist + tiles + perm (one block, LDS atomics)
        __shared__ int hcnt[10], hbase[10], hcur[10], tbase[11];
        if (tid < 10) hcnt[tid] = 0;
        __syncthreads();
        for (int n = tid; n < NN; n += 256) {
            int s = specie[n];
            s = ((unsigned)s < 10) ? s : 0;
            atomicAdd(&hcnt[s], 1);
        }
        __syncthreads();
        if (tid == 0) {
            int run = 0, tc = 0;
            for (int sp = 0; sp < 10; sp++) {
                hbase[sp] = run; hcur[sp] = run; run += hcnt[sp];
                tbase[sp] = tc;  tc += (hcnt[sp] + 15) >> 4;
            }
            tbase[10] = tc;
            *ntiles = tc;
        }
        __syncthreads();
        const int tc = tbase[10];
        for (int ti = tid; ti < tc; ti += 256) {
            int sp = 0;
            while (sp < 9 && ti >= tbase[sp + 1]) sp++;
            const int bb = (ti - tbase[sp]) * 16;
            tiles[ti] = make_int2(hbase[sp] + bb, (sp << 8) | min(16, hcnt[sp] - bb));
        }
        for (int n = tid; n < NN; n += 256) {
            int s = specie[n];
            s = ((unsigned)s < 10) ? s : 0;
            int slot = atomicAdd(&hcur[s], 1);
            if ((unsigned)slot < NN) perm[slot] = n;
        }
    }
}

// ---- pre: perm-tiles, h4q (W_up) + scb (W_skip[sp]) + direct csr fill ----
// h4q: uint4[NN][64]; pair P=16*(d>>5)+(d&15) holds channels c=32wv+row
// (half 0) and c+16 (half 1), each as uint2{pack2(s,v0),pack2(v1,v2)}.
// scb: uint2[NN][128] = {pack2(sc_s,sc_v0), pack2(sc_v1,sc_v2)}.
// csr: int[NN][CAP], slot = atomicAdd(&cnt[r]) — no scan needed.
__global__ __launch_bounds__(256) void k_fill_pre(
    const int* __restrict__ recv, int* __restrict__ cnt, int* __restrict__ csr,
    const float* __restrict__ nf,
    const unsigned short* __restrict__ Tw,
    uint2* __restrict__ h4o,
    const int* __restrict__ perm, const int2* __restrict__ tiles,
    const int* __restrict__ ntiles,
    uint2* __restrict__ scb) {
    if (blockIdx.x >= 640) {  // direct csr fill
        const int e = (blockIdx.x - 640) * 256 + threadIdx.x;
        if (e < EE) {
            int r = recv[e];
            r = ((unsigned)r < NN) ? r : 0;
            int slot = atomicAdd(&cnt[r], 1);
            if (slot < CAP) csr[(r << 7) + slot] = e;
        }
        return;
    }
    const int tile = blockIdx.x;
    if (tile >= *ntiles) return;
    const int2 td = tiles[tile];
    const int base = td.x, sp = td.y >> 8, cnt16 = td.y & 255;
    __shared__ int nodesl[16];
    __shared__ float nfl[16][516];  // pad 516: 2-way banks (was 16-way)
    const int tid = threadIdx.x;
    if (tid < 16) nodesl[tid] = perm[base + ((tid < cnt16) ? tid : 0)];
    __syncthreads();
    {
        for (int i = tid; i < 2048; i += 256) {
            const int r = i >> 7, off4 = (i & 127) * 4;
            *(float4*)&nfl[r][off4] =
                ((const float4*)(nf + (size_t)nodesl[r] * 512))[i & 127];
        }
    }
    __syncthreads();
    const int lane = tid & 63, wv = tid >> 6;
    const int col = lane & 15, quad = lane >> 4;
    const float* rp = nfl[col];
    s16x8 Af[4][4];
#pragma unroll
    for (int kt = 0; kt < 4; kt++) {
        const int ko = kt * 32 + quad * 8;
        const float4 fa = *(const float4*)(rp + ko);
        const float4 fb = *(const float4*)(rp + ko + 4);
        Af[0][kt] = pack8(fa, fb);
#pragma unroll
        for (int i = 0; i < 3; i++) {
            union { s16x8 v; unsigned short u[8]; } A;
#pragma unroll
            for (int j = 0; j < 8; j++) A.u[j] = f2bu(rp[128 + 3 * (ko + j) + i]);
            Af[1 + i][kt] = A.v;
        }
    }
    const unsigned short* Ts = Tw;
    const unsigned short* Tv = Tw + 16384;
    const unsigned short* Tss = Tw + (size_t)(6 + sp) * 16384;
    const unsigned short* Tsv = Tw + (size_t)(16 + sp) * 16384;
#pragma unroll
    for (int nt = 0; nt < 2; nt++) {
        const int d = 32 * wv + 16 * nt + col;
        // ---- up GEMM -> h4q ----
        f32x4 C[4];
#pragma unroll
        for (int m = 0; m < 4; m++) C[m] = (f32x4){0.f, 0.f, 0.f, 0.f};
#pragma unroll
        for (int kt = 0; kt < 4; kt++) {
            const int ko = kt * 32 + quad * 8;
            const s16x8 Bs = *(const s16x8*)&Ts[(size_t)d * 128 + ko];
            const s16x8 Bv = *(const s16x8*)&Tv[(size_t)d * 128 + ko];
            C[0] = __builtin_amdgcn_mfma_f32_16x16x32_bf16(Af[0][kt], Bs, C[0], 0, 0, 0);
#pragma unroll
            for (int i = 0; i < 3; i++)
                C[1 + i] = __builtin_amdgcn_mfma_f32_16x16x32_bf16(Af[1 + i][kt], Bv, C[1 + i], 0, 0, 0);
        }
        const int P = ((d >> 5) << 4) + (d & 15);
        const int half = (d >> 4) & 1;
#pragma unroll
        for (int reg = 0; reg < 4; reg++) {
            const int node = nodesl[quad * 4 + reg];
            h4o[((size_t)node * 64 + P) * 2 + half] =
                make_uint2(pack2(C[0][reg], C[1][reg]), pack2(C[2][reg], C[3][reg]));
        }
        // ---- skip GEMM -> scb ----
        f32x4 CS[4];
#pragma unroll
        for (int m = 0; m < 4; m++) CS[m] = (f32x4){0.f, 0.f, 0.f, 0.f};
#pragma unroll
        for (int kt = 0; kt < 4; kt++) {
            const int ko = kt * 32 + quad * 8;
            const s16x8 Bss = *(const s16x8*)&Tss[(size_t)d * 128 + ko];
            const s16x8 Bsv = *(const s16x8*)&Tsv[(size_t)d * 128 + ko];
            CS[0] = __builtin_amdgcn_mfma_f32_16x16x32_bf16(Af[0][kt], Bss, CS[0], 0, 0, 0);
#pragma unroll
            for (int i = 0; i < 3; i++)
                CS[1 + i] = __builtin_amdgcn_mfma_f32_16x16x32_bf16(Af[1 + i][kt], Bsv, CS[1 + i], 0, 0, 0);
        }
#pragma unroll
        for (int reg = 0; reg < 4; reg++) {
            const int node = nodesl[quad * 4 + reg];
            scb[(size_t)node * 128 + d] =
                make_uint2(pack2(CS[0][reg], CS[1][reg]), pack2(CS[2][reg], CS[3][reg]));
        }
    }
}

// ------- MFMA edge kernel: 1-barrier/chunk pipeline + gather lookahead ------
#define EGRID 1024
__global__ __launch_bounds__(256, 2) void k_edge_mfma(
    const float* __restrict__ vectors,
    const float* __restrict__ radial,
    const int* __restrict__ senders,
    const float* __restrict__ W_rad1,
    const unsigned short* __restrict__ w2t,   // [640][64] bf16
    const uint4* __restrict__ h4q,            // [N][64] channel pairs
    const int* __restrict__ cnt, const int* __restrict__ csr,
    unsigned short* __restrict__ aggb) {      // [N][4][128] bf16 planar
    __shared__ unsigned short w1s[512];
    __shared__ float4 em[3][64];              // 3-slot rotation
    __shared__ float radl[3][64][8];
    __shared__ unsigned short hidb[2 * 64 * 72];  // double buffer
    const int tid = threadIdx.x;
    const int lane = tid & 63, wv = tid >> 6;
    const int row = lane & 15, quad = lane >> 4;
    const int sE = tid >> 2, st = tid & 3;    // stager/hid mapping
    for (int i = tid; i < 512; i += 256) w1s[i] = f2bu(W_rad1[i]);

    s16x8 Bf[2][5][2];
#pragma unroll
    for (int ti = 0; ti < 2; ti++) {
        const int t = 2 * wv + ti;
#pragma unroll
        for (int p = 0; p < 5; p++) {
            const unsigned short* bp =
                w2t + (size_t)(128 * p + 16 * t + row) * 64 + quad * 8;
            Bf[ti][p][0] = *(const s16x8*)(bp);
            Bf[ti][p][1] = *(const s16x8*)(bp + 32);
        }
    }

    // chunk iterator state: cur (computing), nxt (staging), nx2 (csr prefetch)
    // base = N<<7 (fixed-stride CSR), deg = min(cnt[N], CAP)
    int curN = blockIdx.x, curS = curN << 7, curD = min(cnt[curN], CAP), curC0 = 0;
    int nxtN = curN, nxtS = curS, nxtD = curD, nxtC0 = 0;
    {   // adv(nxt)
        nxtC0 += 64;
        if (nxtC0 >= nxtD) {
            nxtN += EGRID;
            if (nxtN < NN) { nxtS = nxtN << 7; nxtD = min(cnt[nxtN], CAP); }
            nxtC0 = 0;
        }
    }
    int nx2N = nxtN, nx2S = nxtS, nx2D = nxtD, nx2C0 = nxtC0;
    if (nx2N < NN) {  // adv(nx2)
        nx2C0 += 64;
        if (nx2C0 >= nx2D) {
            nx2N += EGRID;
            if (nx2N < NN) { nx2S = nx2N << 7; nx2D = min(cnt[nx2N], CAP); }
            nx2C0 = 0;
        }
    }

    // prologue: stage chunk 0 into slot 0 (direct)
    if (st < 2) {
        const int gi = curC0 + sE;
        if (gi < curD) {
            int e = csr[curS + gi];
            e = ((unsigned)e < EE) ? e : 0;
            if (st == 0) {
                int j = senders[e];
                j = ((unsigned)j < NN) ? j : 0;
                const float vx = vectors[e * 3 + 0];
                const float vy = vectors[e * 3 + 1];
                const float vz = vectors[e * 3 + 2];
                const float inr = 1.7320508075688772f /
                    (sqrtf(vx * vx + vy * vy + vz * vz) + 1e-9f);
                em[0][sE] = make_float4(__int_as_float(j), vx * inr, vy * inr, vz * inr);
            } else {
                *(float4*)&radl[0][sE][0] = *(const float4*)(radial + (size_t)e * 8);
                *(float4*)&radl[0][sE][4] = *(const float4*)(radial + (size_t)e * 8 + 4);
            }
        } else {
            if (st == 0) em[0][sE] = make_float4(0.f, 0.f, 0.f, 0.f);
            else {
                *(float4*)&radl[0][sE][0] = make_float4(0.f, 0.f, 0.f, 0.f);
                *(float4*)&radl[0][sE][4] = make_float4(0.f, 0.f, 0.f, 0.f);
            }
        }
    }
    // prologue csr lookahead for chunk 1 (nxt)
    int eReg = -1;
    if (nxtN < NN && st < 2) {
        const int gi = nxtC0 + sE;
        if (gi < nxtD) {
            int e = csr[nxtS + gi];
            eReg = ((unsigned)e < EE) ? e : 0;
        }
    }
    __syncthreads();

    float acc_s[2] = {0.f, 0.f}, av0[2] = {0.f, 0.f},
          av1[2] = {0.f, 0.f}, av2[2] = {0.f, 0.f};
    int cs = 0, hbI = 0;
    while (true) {
        const int ws = (cs == 2) ? 0 : cs + 1;
        const bool hasNxt = (nxtN < NN);
        const float4* emc = em[cs];
        const float* emf = (const float*)emc;
        // ---- A0: issue group-0 h4q gathers for CURRENT chunk (em[cs] is
        //      valid since the previous barrier) -> in flight across B/C ----
        uint4 hqA[4];
#pragma unroll
        for (int rg = 0; rg < 4; rg++) {
            const int j = __float_as_int(emf[(quad * 4 + rg) * 4]);
            hqA[rg] = h4q[(size_t)j * 64 + (wv << 4) + row];
        }
        // ---- A1: gathers for next chunk from eReg; csr prefetch for nx2 ----
        bool sv = false;
        float4 ra0 = make_float4(0.f, 0.f, 0.f, 0.f);
        float4 ra1 = make_float4(0.f, 0.f, 0.f, 0.f);
        if (hasNxt && st < 2 && eReg >= 0) {
            sv = true;
            const int e = eReg;
            if (st == 0) {
                int j = senders[e];
                j = ((unsigned)j < NN) ? j : 0;
                ra0 = make_float4(vectors[e * 3 + 0], vectors[e * 3 + 1],
                                  vectors[e * 3 + 2], __int_as_float(j));
            } else {
                ra0 = *(const float4*)(radial + (size_t)e * 8);
                ra1 = *(const float4*)(radial + (size_t)e * 8 + 4);
            }
        }
        int eRegN = -1;
        if (nx2N < NN && st < 2) {
            const int gi = nx2C0 + sE;
            if (gi < nx2D) {
                int e = csr[nx2S + gi];
                eRegN = ((unsigned)e < EE) ? e : 0;
            }
        }
        // ---- B: hid MLP for current chunk (skip empty slots) ----
        const int glimC = min(64, curD - curC0);
        {
            const int g16C = (glimC + 15) & ~15;
            unsigned short* hb = hidb + hbI * 4608;
            const int u0 = st * 16;
            if (sE < glimC) {
                float rr[8];
                *(float4*)&rr[0] = *(const float4*)&radl[cs][sE][0];
                *(float4*)&rr[4] = *(const float4*)&radl[cs][sE][4];
#pragma unroll
                for (int h = 0; h < 2; h++) {
                    float a[8];
#pragma unroll
                    for (int u = 0; u < 8; u++) a[u] = 0.f;
#pragma unroll
                    for (int r = 0; r < 8; r++) {
                        const uint4 wa = *(const uint4*)&w1s[r * 64 + u0 + h * 8];
                        const float f = rr[r];
                        a[0] += f * bflo(wa.x); a[1] += f * bfhi(wa.x);
                        a[2] += f * bflo(wa.y); a[3] += f * bfhi(wa.y);
                        a[4] += f * bflo(wa.z); a[5] += f * bfhi(wa.z);
                        a[6] += f * bflo(wa.w); a[7] += f * bfhi(wa.w);
                    }
                    unsigned o[4];
#pragma unroll
                    for (int k = 0; k < 4; k++) {
                        const float s0 = a[2 * k] / (1.f + __expf(-a[2 * k]));
                        const float s1 = a[2 * k + 1] / (1.f + __expf(-a[2 * k + 1]));
                        o[k] = pack2(s0, s1);
                    }
                    *(uint4*)&hb[sE * 72 + u0 + h * 8] = make_uint4(o[0], o[1], o[2], o[3]);
                }
            } else if (sE < g16C) {
                *(uint4*)&hb[sE * 72 + u0] = make_uint4(0, 0, 0, 0);
                *(uint4*)&hb[sE * 72 + u0 + 8] = make_uint4(0, 0, 0, 0);
            }
        }
        // ---- C: store staged data for next chunk ----
        if (hasNxt && st < 2) {
            if (st == 0) {
                if (sv) {
                    const float vx = ra0.x, vy = ra0.y, vz = ra0.z;
                    const float inr = 1.7320508075688772f /
                        (sqrtf(vx * vx + vy * vy + vz * vz) + 1e-9f);
                    em[ws][sE] = make_float4(ra0.w, vx * inr, vy * inr, vz * inr);
                } else {
                    em[ws][sE] = make_float4(0.f, 0.f, 0.f, 0.f);
                }
            } else {
                *(float4*)&radl[ws][sE][0] = ra0;
                *(float4*)&radl[ws][sE][4] = ra1;
            }
        }
        __syncthreads();
        // ---- E: MFMA + combine for current chunk (boosted priority) ----
        {
            __builtin_amdgcn_s_setprio(1);
            const unsigned short* hb = hidb + hbI * 4608;
            for (int g0 = 0; g0 < glimC; g0 += 16) {
                const s16x8 A0 = *(const s16x8*)&hb[(g0 + row) * 72 + quad * 8];
                const s16x8 A1 = *(const s16x8*)&hb[(g0 + row) * 72 + 32 + quad * 8];
                float4 mm[4];
#pragma unroll
                for (int rg = 0; rg < 4; rg++) mm[rg] = emc[g0 + quad * 4 + rg];
                // prefetch next group's h4q rows
                const bool more = (g0 + 16) < glimC;
                uint4 hqB[4];
                if (more) {
#pragma unroll
                    for (int rg = 0; rg < 4; rg++) {
                        const int j = __float_as_int(emf[(g0 + 16 + quad * 4 + rg) * 4]);
                        hqB[rg] = h4q[(size_t)j * 64 + (wv << 4) + row];
                    }
                }
#pragma unroll
                for (int ti = 0; ti < 2; ti++) {
                    float sj[4], a0r[4], a1r[4], a2r[4];
#pragma unroll
                    for (int rg = 0; rg < 4; rg++) {
                        const unsigned wx = ti ? hqA[rg].z : hqA[rg].x;
                        const unsigned wy = ti ? hqA[rg].w : hqA[rg].y;
                        sj[rg] = bflo(wx); a0r[rg] = bfhi(wx);
                        a1r[rg] = bflo(wy); a2r[rg] = bfhi(wy);
                    }
#pragma unroll
                    for (int p = 0; p < 5; p++) {
                        f32x4 z = {0.f, 0.f, 0.f, 0.f};
                        z = __builtin_amdgcn_mfma_f32_16x16x32_bf16(A0, Bf[ti][p][0], z, 0, 0, 0);
                        z = __builtin_amdgcn_mfma_f32_16x16x32_bf16(A1, Bf[ti][p][1], z, 0, 0, 0);
#pragma unroll
                        for (int rg = 0; rg < 4; rg++) {
                            const float w = z[rg];
                            const float y0 = mm[rg].y, y1 = mm[rg].z, y2 = mm[rg].w;
                            if (p == 0) {
                                acc_s[ti] += w * sj[rg];
                            } else if (p == 1) {
                                const float wsj = w * sj[rg];
                                av0[ti] += wsj * y0;
                                av1[ti] += wsj * y1;
                                av2[ti] += wsj * y2;
                            } else if (p == 2) {
                                av0[ti] += w * a0r[rg];
                                av1[ti] += w * a1r[rg];
                                av2[ti] += w * a2r[rg];
                            } else if (p == 3) {
                                acc_s[ti] += w * (a0r[rg] * y0 + a1r[rg] * y1 +
                                                  a2r[rg] * y2);
                            } else {
                                av0[ti] += w * (a1r[rg] * y2 - a2r[rg] * y1);
                                av1[ti] += w * (a2r[rg] * y0 - a0r[rg] * y2);
                                av2[ti] += w * (a0r[rg] * y1 - a1r[rg] * y0);
                            }
                        }
                    }
                }
                if (more) {
#pragma unroll
                    for (int rg = 0; rg < 4; rg++) hqA[rg] = hqB[rg];
                }
            }
            __builtin_amdgcn_s_setprio(0);
            // finalize node on its last chunk
            if (curC0 + 64 >= curD) {
#pragma unroll
                for (int ti = 0; ti < 2; ti++) {
                    acc_s[ti] += __shfl_xor(acc_s[ti], 16); acc_s[ti] += __shfl_xor(acc_s[ti], 32);
                    av0[ti] += __shfl_xor(av0[ti], 16);     av0[ti] += __shfl_xor(av0[ti], 32);
                    av1[ti] += __shfl_xor(av1[ti], 16);     av1[ti] += __shfl_xor(av1[ti], 32);
                    av2[ti] += __shfl_xor(av2[ti], 16);     av2[ti] += __shfl_xor(av2[ti], 32);
                }
                if (lane < 16) {
                    unsigned short* og = aggb + (size_t)curN * 512;
#pragma unroll
                    for (int ti = 0; ti < 2; ti++) {
                        const int cc = 16 * (2 * wv + ti) + lane;
                        og[cc] = f2bu(acc_s[ti]);
                        og[128 + cc] = f2bu(av0[ti]);
                        og[256 + cc] = f2bu(av1[ti]);
                        og[384 + cc] = f2bu(av2[ti]);
                    }
                }
                acc_s[0] = acc_s[1] = 0.f; av0[0] = av0[1] = 0.f;
                av1[0] = av1[1] = 0.f;     av2[0] = av2[1] = 0.f;
            }
        }
        if (!hasNxt) break;
        // advance: cur <- nxt, nxt <- nx2, adv(nx2), eReg <- eRegN
        curN = nxtN; curS = nxtS; curD = nxtD; curC0 = nxtC0;
        nxtN = nx2N; nxtS = nx2S; nxtD = nx2D; nxtC0 = nx2C0;
        if (nx2N < NN) {
            nx2C0 += 64;
            if (nx2C0 >= nx2D) {
                nx2N += EGRID;
                if (nx2N < NN) { nx2S = nx2N << 7; nx2D = min(cnt[nx2N], CAP); }
                nx2C0 = 0;
            }
        }
        eReg = eRegN;
        cs = ws; hbI ^= 1;
    }
}

// -------- post: down GEMM -> prod -> P via LDS -> lin GEMM + scb + out -----
__global__ __launch_bounds__(256) void k_post_mfma(
    const unsigned short* __restrict__ aggb,
    const int* __restrict__ perm,
    const int2* __restrict__ tiles,
    const int* __restrict__ ntiles,
    const unsigned short* __restrict__ Tw,
    const float* __restrict__ Wps,
    const float* __restrict__ Wpv,
    const float* __restrict__ Wro,
    const uint2* __restrict__ scb,
    float* __restrict__ dout) {
    const int tile = blockIdx.x;
    if (tile >= *ntiles) return;
    const int2 td = tiles[tile];
    const int base = td.x, sp = td.y >> 8, cnt = td.y & 255;
    __shared__ int nodesl[16];
    __shared__ float rol[16];
    __shared__ unsigned short Pl[4][16][136];  // pad 136: 16B-aligned, 2-way
    const int tid = threadIdx.x;
    if (tid < 16) {
        nodesl[tid] = perm[base + ((tid < cnt) ? tid : 0)];
        rol[tid] = 0.f;
    }
    __syncthreads();
    const int lane = tid & 63, wv = tid >> 6;
    const int col = lane & 15, quad = lane >> 4;
    const int aN = nodesl[col];
    const unsigned short* Tds = Tw + (size_t)2 * 16384;
    const unsigned short* Tdv = Tw + (size_t)3 * 16384;
    const unsigned short* Tls = Tw + (size_t)4 * 16384;
    const unsigned short* Tlv = Tw + (size_t)5 * 16384;
#pragma unroll
    for (int nt = 0; nt < 2; nt++) {
        const int d = 32 * wv + 16 * nt + col;
        f32x4 CF[4];
#pragma unroll
        for (int m = 0; m < 4; m++) CF[m] = (f32x4){0.f, 0.f, 0.f, 0.f};
#pragma unroll
        for (int kt = 0; kt < 4; kt++) {
            const int ko = kt * 32 + quad * 8;
            const s16x8 Bs = *(const s16x8*)&Tds[(size_t)d * 128 + ko];
            const s16x8 Bv = *(const s16x8*)&Tdv[(size_t)d * 128 + ko];
#pragma unroll
            for (int m = 0; m < 4; m++) {
                const s16x8 A = *(const s16x8*)&aggb[(size_t)aN * 512 + m * 128 + ko];
                CF[m] = __builtin_amdgcn_mfma_f32_16x16x32_bf16(A, m ? Bv : Bs, CF[m], 0, 0, 0);
            }
        }
        const float wps0 = Wps[sp * 384 + d];
        const float wps1 = Wps[sp * 384 + 128 + d];
        const float wps2 = Wps[sp * 384 + 256 + d];
        const float wpv0 = Wpv[sp * 256 + d];
        const float wpv1 = Wpv[sp * 256 + 128 + d];
#pragma unroll
        for (int reg = 0; reg < 4; reg++) {
            const float fs = CF[0][reg] * FEPS;
            const float f0 = CF[1][reg] * FEPS;
            const float f1 = CF[2][reg] * FEPS;
            const float f2 = CF[3][reg] * FEPS;
            const float ps = fs * wps0 + fs * fs * wps1 + (f0 * f0 + f1 * f1 + f2 * f2) * wps2;
            const float pb = wpv0 + fs * wpv1;
            const int r = quad * 4 + reg;
            Pl[0][r][d] = f2bu(ps);
            Pl[1][r][d] = f2bu(f0 * pb);
            Pl[2][r][d] = f2bu(f1 * pb);
            Pl[3][r][d] = f2bu(f2 * pb);
        }
    }
    __syncthreads();
    // prefetch scb gathers for both nt (latency hidden under the lin GEMMs;
    // nodesl[] is clamp-initialized so unguarded addressing is safe)
    uint2 svp[2][4];
#pragma unroll
    for (int nt = 0; nt < 2; nt++) {
        const int d = 32 * wv + 16 * nt + col;
#pragma unroll
        for (int reg = 0; reg < 4; reg++) {
            const int r = quad * 4 + reg;
            svp[nt][reg] = scb[(size_t)nodesl[r] * 128 + d];
        }
    }
#pragma unroll
    for (int nt = 0; nt < 2; nt++) {
        const int d = 32 * wv + 16 * nt + col;
        f32x4 CL[4];
#pragma unroll
        for (int m = 0; m < 4; m++) CL[m] = (f32x4){0.f, 0.f, 0.f, 0.f};
#pragma unroll
        for (int kt = 0; kt < 4; kt++) {
            const int ko = kt * 32 + quad * 8;
            const s16x8 Bls = *(const s16x8*)&Tls[(size_t)d * 128 + ko];
            const s16x8 Blv = *(const s16x8*)&Tlv[(size_t)d * 128 + ko];
#pragma unroll
            for (int m = 0; m < 4; m++) {
                const s16x8 A = *(const s16x8*)&Pl[m][col][ko];
                CL[m] = __builtin_amdgcn_mfma_f32_16x16x32_bf16(A, m ? Blv : Bls, CL[m], 0, 0, 0);
            }
        }
        const float wro = Wro[d];
#pragma unroll
        for (int reg = 0; reg < 4; reg++) {
            const int r = quad * 4 + reg;
            if (r < cnt) {
                const int node = nodesl[r];
                const uint2 sv = svp[nt][reg];
                const float outs = CL[0][reg] + bflo(sv.x);
                const float o0 = CL[1][reg] + bfhi(sv.x);
                const float o1 = CL[2][reg] + bflo(sv.y);
                const float o2 = CL[3][reg] + bfhi(sv.y);
                float* o = dout + NN + (size_t)node * 512;
                o[d] = outs;
                o[128 + 3 * d + 0] = o0;
                o[128 + 3 * d + 1] = o1;
                o[128 + 3 * d + 2] = o2;
                atomicAdd(&rol[r], outs * wro);
            }
        }
    }
    __syncthreads();
    if (tid < 16 && tid < cnt) dout[nodesl[tid]] = rol[tid];
}

extern "C" void kernel_launch(void* const* d_in, const int* in_sizes, int n_in,
                              void* d_out, int out_size, void* d_ws, size_t ws_size,
                              hipStream_t stream) {
    const float* vectors    = (const float*)d_in[0];
    const float* node_feats = (const float*)d_in[1];
    const int*   specie     = (const int*)d_in[2];
    const float* radial     = (const float*)d_in[3];
    const int*   senders    = (const int*)d_in[4];
    const int*   receivers  = (const int*)d_in[5];
    const float* W_up_s     = (const float*)d_in[6];
    const float* W_up_v     = (const float*)d_in[7];
    const float* W_rad1     = (const float*)d_in[8];
    const float* W_rad2     = (const float*)d_in[9];
    const float* W_down_s   = (const float*)d_in[10];
    const float* W_down_v   = (const float*)d_in[11];
    const float* W_skip_s   = (const float*)d_in[12];
    const float* W_skip_v   = (const float*)d_in[13];
    const float* W_prod_s   = (const float*)d_in[14];
    const float* W_prod_v   = (const float*)d_in[15];
    const float* W_lin_s    = (const float*)d_in[16];
    const float* W_lin_v    = (const float*)d_in[17];
    const float* W_ro       = (const float*)d_in[18];
    float* out = (float*)d_out;

    // workspace carve (~37 MB)
    char* w = (char*)d_ws;
    auto align256 = [](size_t x) { return (x + 255) & ~(size_t)255; };
    int* cnt  = (int*)w;              w += align256((size_t)NN * 4);
    int* csr  = (int*)w;              w += align256((size_t)NN * CAP * 4);
    uint4* h4q = (uint4*)w;           w += align256((size_t)NN * 64 * 16);
    unsigned short* aggb = (unsigned short*)w;  w += align256((size_t)NN * 512 * 2);
    unsigned short* w2t  = (unsigned short*)w;  w += align256((size_t)W2N * 2);
    unsigned short* Tw   = (unsigned short*)w;  w += align256((size_t)TWN * 2);
    int* perm   = (int*)w;            w += align256((size_t)NN * 4);
    int2* tiles = (int2*)w;           w += align256((size_t)640 * 8);
    int* ntiles = (int*)w;            w += align256(4);
    uint2* scb  = (uint2*)w;          w += align256((size_t)NN * 128 * 8);

    hipMemsetAsync(cnt, 0, (size_t)NN * 4, stream);
    k_prep_spec<<<26 + PREPX + 1, 256, 0, stream>>>(
        W_up_s, W_up_v, W_down_s, W_down_v, W_lin_s, W_lin_v,
        W_skip_s, W_skip_v, W_rad2, Tw, w2t, specie, perm, tiles, ntiles);
    k_fill_pre<<<640 + HISTB, 256, 0, stream>>>(
        receivers, cnt, csr, node_feats, Tw, (uint2*)h4q,
        perm, tiles, ntiles, scb);
    k_edge_mfma<<<EGRID, 256, 0, stream>>>(vectors, radial, senders, W_rad1,
                                           w2t, h4q, cnt, csr, aggb);
    k_post_mfma<<<640, 256, 0, stream>>>(aggb, perm, tiles, ntiles,
                                         Tw, W_prod_s, W_prod_v, W_ro, scb, out);
}